// Round 1
// baseline (133.413 us; speedup 1.0000x reference)
//
#include <hip/hip_runtime.h>

// STU layer: out[b,t,e] = sum_{k,d} phi[t,k] * C[b,t,k,d] * W[k,e,d],
//            C = cumsum_t(phi[t,k] * x[b,t,d])
// Strategy: out = A @ WT^T as one bf16 GEMM (M=16384, Kdim=4096, N=256),
//   A[bt, d*16+k]  = phi[t,k]*C[b,t,k,d]   (built on the fly from chunk-prefix states)
//   WT[e, d*16+k]  = W[k,e,d]
//
// B=4, T=4096, D=256, K=16. Tc=64 chunks (NC=64 per batch).

typedef __bf16 bf16x8 __attribute__((ext_vector_type(8)));
typedef float  f32x4  __attribute__((ext_vector_type(4)));
typedef unsigned short u16;

__device__ static inline u16 f2bf(float f) {          // round-to-nearest-even f32->bf16
    unsigned int u = __float_as_uint(f);
    u = (u + 0x7fffu + ((u >> 16) & 1u)) >> 16;
    return (u16)u;
}

__device__ static inline void gload16(const void* g, void* l) {
    __builtin_amdgcn_global_load_lds((const __attribute__((address_space(1))) void*)g,
                                     (__attribute__((address_space(3))) void*)l, 16, 0, 0);
}

// ---------------- k0: WT[e][d*16+k] = bf16(W[k][e][d]) ----------------
__global__ __launch_bounds__(256) void k0_wt(const float* __restrict__ W, u16* __restrict__ WT) {
    const int e = blockIdx.x, d = threadIdx.x;
    union { u16 u[16]; uint4 v[2]; } ob;
#pragma unroll
    for (int k = 0; k < 16; ++k)
        ob.u[k] = f2bf(W[((size_t)k * 256 + e) * 256 + d]);
    uint4* dst = (uint4*)(WT + (size_t)e * 4096 + d * 16);
    dst[0] = ob.v[0]; dst[1] = ob.v[1];
}

// ---------------- k1: chunk partial sums U[b,c,d,k] = sum_{s in chunk} phi*x ----------------
__global__ __launch_bounds__(256) void k1_sums(const float* __restrict__ x,
                                               const float* __restrict__ phi,
                                               float* __restrict__ U) {
    __shared__ float phis[1024];
    const int tid = threadIdx.x;
    const int b = blockIdx.x, c = blockIdx.y;
    const int t0 = c * 64;
#pragma unroll
    for (int i = 0; i < 4; ++i) phis[tid + i * 256] = phi[t0 * 16 + tid + i * 256];
    __syncthreads();
    float acc[16];
#pragma unroll
    for (int k = 0; k < 16; ++k) acc[k] = 0.f;
    for (int s = 0; s < 64; ++s) {
        const float xv = x[(size_t)((b << 12) + t0 + s) * 256 + tid];
        union { float f[16]; float4 v[4]; } pv;
#pragma unroll
        for (int j = 0; j < 4; ++j) pv.v[j] = *(const float4*)&phis[s * 16 + j * 4];
#pragma unroll
        for (int k = 0; k < 16; ++k) acc[k] = fmaf(pv.f[k], xv, acc[k]);
    }
    float* Up = U + ((size_t)((b * 64 + c) * 256 + tid)) * 16;
#pragma unroll
    for (int k = 0; k < 16; ++k) Up[k] = acc[k];
}

// ---------------- k2: exclusive scan of U over c (in place) ----------------
__global__ __launch_bounds__(256) void k2_scan(float* __restrict__ U) {
    const int b = blockIdx.x, dt = blockIdx.y;   // grid (4,16)
    const int dk = dt * 256 + threadIdx.x;       // (d*16+k)
    float* base = U + (size_t)b * 64 * 4096 + dk;
    float runv = 0.f;
    for (int cg = 0; cg < 4; ++cg) {
        float v[16];
#pragma unroll
        for (int j = 0; j < 16; ++j) v[j] = base[(size_t)(cg * 16 + j) * 4096];
#pragma unroll
        for (int j = 0; j < 16; ++j) {
            const float t = v[j];
            base[(size_t)(cg * 16 + j) * 4096] = runv;
            runv += t;
        }
    }
}

// ---------------- k3: build A rows (slab-local) ----------------
__global__ __launch_bounds__(256) void k3_build(const float* __restrict__ x,
                                                const float* __restrict__ phi,
                                                const float* __restrict__ U,
                                                u16* __restrict__ Abuf, int Mbase) {
    __shared__ float phis[1024];
    const int tid = threadIdx.x;
    const int ch  = blockIdx.x;
    const int bt0 = Mbase + ch * 64;
    const int b   = bt0 >> 12;
    const int t0  = bt0 & 4095;
    const int c   = t0 >> 6;
#pragma unroll
    for (int i = 0; i < 4; ++i) phis[tid + i * 256] = phi[t0 * 16 + tid + i * 256];
    __syncthreads();
    const int d = tid;
    float run[16];
    const float* Up = U + ((size_t)((b * 64 + c) * 256 + d)) * 16;
#pragma unroll
    for (int k = 0; k < 16; ++k) run[k] = Up[k];
    for (int s = 0; s < 64; ++s) {
        const float xv = x[(size_t)(bt0 + s) * 256 + d];
        union { float f[16]; float4 v[4]; } pv;
#pragma unroll
        for (int j = 0; j < 4; ++j) pv.v[j] = *(const float4*)&phis[s * 16 + j * 4];
        union { u16 u[16]; uint4 v[2]; } ob;
#pragma unroll
        for (int k = 0; k < 16; ++k) {
            run[k] = fmaf(pv.f[k], xv, run[k]);
            ob.u[k] = f2bf(pv.f[k] * run[k]);
        }
        uint4* dst = (uint4*)(Abuf + (size_t)(ch * 64 + s) * 4096 + d * 16);
        dst[0] = ob.v[0]; dst[1] = ob.v[1];
    }
}

// ---------------- k4: GEMM out += A(slab) @ WT^T, K-split=2 via atomics ----------------
// BM=128, BN=256(full N), BK=64; 512 threads = 8 waves (2M x 4N), each wave 64x64.
__global__ __launch_bounds__(512) void k4_gemm(const u16* __restrict__ A,
                                               const u16* __restrict__ BT,
                                               float* __restrict__ C, int Mbase) {
    __shared__ __align__(16) char smem[49152];   // A tile 16KB @0, B tile 32KB @16384
    const int tid = threadIdx.x;
    const int m0  = blockIdx.x * 128;            // slab-local row
    const int ks  = blockIdx.y;                  // kd half: 0 or 1
    const int w = tid >> 6, l = tid & 63;
    const int wm = (w >> 2) * 64, wn = (w & 3) * 64;
    const int lg = l >> 4, lr = l & 15;
    f32x4 acc[4][4] = {};

    const char* Ab = (const char*)A;
    const char* Bb = (const char*)BT;
    const int rst = tid >> 3;            // 0..63
    const int cb  = (tid & 7) * 16;      // 16B col within 128B row

    for (int kt = 0; kt < 32; ++kt) {
        const int kofs = ks * 4096 + kt * 128;   // byte offset within 8192B row
#pragma unroll
        for (int c = 0; c < 2; ++c) {            // A: 128 rows
            const int row = c * 64 + rst;
            gload16(Ab + (size_t)(m0 + row) * 8192 + kofs + (cb ^ ((row & 7) << 4)),
                    smem + c * 8192 + tid * 16);
        }
#pragma unroll
        for (int c = 0; c < 4; ++c) {            // B: 256 rows (all of N)
            const int row = c * 64 + rst;
            gload16(Bb + (size_t)row * 8192 + kofs + (cb ^ ((row & 7) << 4)),
                    smem + 16384 + c * 8192 + tid * 16);
        }
        __syncthreads();
#pragma unroll
        for (int kk = 0; kk < 2; ++kk) {
            const int kb = kk * 64 + lg * 16;
            bf16x8 af[4], bfv[4];
#pragma unroll
            for (int mi = 0; mi < 4; ++mi) {
                const int r = wm + mi * 16 + lr;
                af[mi] = *(const bf16x8*)(smem + (((r * 128) + kb) ^ ((r & 7) << 4)));
            }
#pragma unroll
            for (int ni = 0; ni < 4; ++ni) {
                const int n = wn + ni * 16 + lr;
                bfv[ni] = *(const bf16x8*)(smem + 16384 + (((n * 128) + kb) ^ ((n & 7) << 4)));
            }
#pragma unroll
            for (int mi = 0; mi < 4; ++mi)
#pragma unroll
                for (int ni = 0; ni < 4; ++ni)
                    acc[mi][ni] = __builtin_amdgcn_mfma_f32_16x16x32_bf16(af[mi], bfv[ni], acc[mi][ni], 0, 0, 0);
        }
        __syncthreads();
    }
    // epilogue: two contributions per out element (ks=0/1) -> bitwise-deterministic f32 add
#pragma unroll
    for (int mi = 0; mi < 4; ++mi)
#pragma unroll
        for (int ni = 0; ni < 4; ++ni)
#pragma unroll
            for (int r = 0; r < 4; ++r) {
                const int row = Mbase + m0 + wm + mi * 16 + lg * 4 + r;
                const int col = wn + ni * 16 + lr;
                unsafeAtomicAdd(&C[(size_t)row * 256 + col], acc[mi][ni][r]);
            }
}

extern "C" void kernel_launch(void* const* d_in, const int* in_sizes, int n_in,
                              void* d_out, int out_size, void* d_ws, size_t ws_size,
                              hipStream_t stream) {
    const float* x   = (const float*)d_in[0];   // (4,4096,256)
    const float* W   = (const float*)d_in[1];   // (16,256,256)
    const float* phi = (const float*)d_in[2];   // (4096,16)
    float* out = (float*)d_out;                 // (4,4096,256) f32

    char* ws = (char*)d_ws;
    u16*   WT   = (u16*)ws;                        // 2 MB
    float* U    = (float*)(ws + (2u << 20));       // 4 MB
    u16*   Abuf = (u16*)(ws + (6u << 20));         // SR*8192 bytes

    const size_t fixed = 6u << 20;
    int SR = 16384;                                // slab rows (bt), shrink if ws is small
    while (SR > 512 && fixed + (size_t)SR * 8192 > ws_size) SR >>= 1;
    const int nslab = 16384 / SR;

    hipMemsetAsync(d_out, 0, (size_t)out_size * sizeof(float), stream);
    k0_wt  <<<256, 256, 0, stream>>>(W, WT);
    k1_sums<<<dim3(4, 64), 256, 0, stream>>>(x, phi, U);
    k2_scan<<<dim3(4, 16), 256, 0, stream>>>(U);
    for (int s = 0; s < nslab; ++s) {
        const int Mbase = s * SR;
        k3_build<<<SR / 64, 256, 0, stream>>>(x, phi, U, Abuf, Mbase);
        k4_gemm <<<dim3(SR / 128, 2), 512, 0, stream>>>(Abuf, WT, out, Mbase);
    }
}

// Round 2
// 129.220 us; speedup vs baseline: 1.0324x; 1.0324x over previous
//
#include <hip/hip_runtime.h>

// STU layer: out[b,t,e] = sum_{k,d} phi[t,k] * C[b,t,k,d] * W[k,e,d],
//            C = cumsum_t(phi[t,k] * x[b,t,d])
// out = A @ WT^T as one bf16 GEMM (M=16384, Kdim=4096, N=256),
//   A[bt, d*16+k]  = phi[t,k]*C[b,t,k,d]
//   WT[e, d*16+k]  = W[k,e,d]
// B=4, T=4096, D=256, K=16. Chunk CH=16 (NC=256 chunks per batch).
// U (chunk-prefix states, 16MB) aliases d_out: consumed by k3 before memset+k4.

typedef __bf16 bf16x8 __attribute__((ext_vector_type(8)));
typedef float  f32x4  __attribute__((ext_vector_type(4)));
typedef unsigned short u16;

__device__ static inline u16 f2bf(float f) {          // RNE f32->bf16
    unsigned int u = __float_as_uint(f);
    u = (u + 0x7fffu + ((u >> 16) & 1u)) >> 16;
    return (u16)u;
}

__device__ static inline void gload16(const void* g, void* l) {
    __builtin_amdgcn_global_load_lds((const __attribute__((address_space(1))) void*)g,
                                     (__attribute__((address_space(3))) void*)l, 16, 0, 0);
}

// ---------------- k0: WT[e][d*16+k] = bf16(W[k][e][d]) ----------------
__global__ __launch_bounds__(256) void k0_wt(const float* __restrict__ W, u16* __restrict__ WT) {
    const int e = blockIdx.x, d = threadIdx.x;
    union { u16 u[16]; uint4 v[2]; } ob;
#pragma unroll
    for (int k = 0; k < 16; ++k)
        ob.u[k] = f2bf(W[((size_t)k * 256 + e) * 256 + d]);
    uint4* dst = (uint4*)(WT + (size_t)e * 4096 + d * 16);
    dst[0] = ob.v[0]; dst[1] = ob.v[1];
}

// ---------------- k1: chunk sums U[b,c,d,k] = sum_{s in 16-chunk} phi*x ----------------
__global__ __launch_bounds__(256) void k1_sums(const float* __restrict__ x,
                                               const float* __restrict__ phi,
                                               float* __restrict__ U) {
    __shared__ float phis[256];
    const int tid = threadIdx.x;
    const int b = blockIdx.x, c = blockIdx.y;
    const int t0 = c * 16;
    phis[tid] = phi[t0 * 16 + tid];
    __syncthreads();
    float acc[16];
#pragma unroll
    for (int k = 0; k < 16; ++k) acc[k] = 0.f;
    for (int s = 0; s < 16; ++s) {
        const float xv = x[(size_t)((b << 12) + t0 + s) * 256 + tid];
        union { float f[16]; float4 v[4]; } pv;
#pragma unroll
        for (int j = 0; j < 4; ++j) pv.v[j] = *(const float4*)&phis[s * 16 + j * 4];
#pragma unroll
        for (int k = 0; k < 16; ++k) acc[k] = fmaf(pv.f[k], xv, acc[k]);
    }
    float4* Up = (float4*)(U + ((size_t)((b * 256 + c) * 256 + tid)) * 16);
    union { float f[16]; float4 v[4]; } ov;
#pragma unroll
    for (int k = 0; k < 16; ++k) ov.f[k] = acc[k];
#pragma unroll
    for (int j = 0; j < 4; ++j) Up[j] = ov.v[j];
}

// ---------------- k2: exclusive scan of U over c (in place), 256 chunks ----------------
__global__ __launch_bounds__(256) void k2_scan(float* __restrict__ U) {
    const int b = blockIdx.x;                       // grid (4,16)
    const int dk = blockIdx.y * 256 + threadIdx.x;  // (d*16+k)
    float* base = U + (size_t)b * 1048576 + dk;
    float runv = 0.f;
    for (int g = 0; g < 16; ++g) {
        float v[16];
#pragma unroll
        for (int j = 0; j < 16; ++j) v[j] = base[(size_t)(g * 16 + j) * 4096];
#pragma unroll
        for (int j = 0; j < 16; ++j) {
            const float t = v[j];
            base[(size_t)(g * 16 + j) * 4096] = runv;
            runv += t;
        }
    }
}

// ---------------- k3: build A rows (one 16-chunk per block) ----------------
__global__ __launch_bounds__(256) void k3_build(const float* __restrict__ x,
                                                const float* __restrict__ phi,
                                                const float* __restrict__ U,
                                                u16* __restrict__ Abuf) {
    __shared__ float phis[256];
    const int tid = threadIdx.x;
    const int ch  = blockIdx.x;          // 0..1023
    const int bt0 = ch * 16;
    const int b   = bt0 >> 12;
    const int t0  = bt0 & 4095;
    const int c   = t0 >> 4;
    phis[tid] = phi[t0 * 16 + tid];
    __syncthreads();
    const int d = tid;
    union { float f[16]; float4 v[4]; } run;
    const float4* Up = (const float4*)(U + ((size_t)((b * 256 + c) * 256 + d)) * 16);
#pragma unroll
    for (int j = 0; j < 4; ++j) run.v[j] = Up[j];
    for (int s = 0; s < 16; ++s) {
        const float xv = x[(size_t)(bt0 + s) * 256 + d];
        union { float f[16]; float4 v[4]; } pv;
#pragma unroll
        for (int j = 0; j < 4; ++j) pv.v[j] = *(const float4*)&phis[s * 16 + j * 4];
        union { u16 u[16]; uint4 v[2]; } ob;
#pragma unroll
        for (int k = 0; k < 16; ++k) {
            run.f[k] = fmaf(pv.f[k], xv, run.f[k]);
            ob.u[k] = f2bf(pv.f[k] * run.f[k]);
        }
        uint4* dst = (uint4*)(Abuf + (size_t)(bt0 + s) * 4096 + d * 16);
        dst[0] = ob.v[0]; dst[1] = ob.v[1];
    }
}

// ---------------- k4: GEMM out += A @ WT^T, K-split=2 via atomics ----------------
// BM=64, BN=256(full N), BK=64; 512 threads = 8 waves (2M x 4N), wave tile 32x64.
// grid (256, 2) = 512 blocks -> ~3 blocks/CU for barrier-drain overlap.
__global__ __launch_bounds__(512, 6) void k4_gemm(const u16* __restrict__ A,
                                                  const u16* __restrict__ BT,
                                                  float* __restrict__ C) {
    __shared__ __align__(16) char smem[40960];   // A tile 8KB @0, B tile 32KB @8192
    const int tid = threadIdx.x;
    const int m0  = blockIdx.x * 64;
    const int ks  = blockIdx.y;                  // kdim half: 0 or 1
    const int w = tid >> 6, l = tid & 63;
    const int wm = (w >> 2) * 32, wn = (w & 3) * 64;
    const int lg = l >> 4, lr = l & 15;
    f32x4 acc[2][4] = {};

    const char* Ab = (const char*)A;
    const char* Bb = (const char*)BT;
    const int rst = tid >> 3;            // 0..63
    const int cb  = (tid & 7) * 16;      // 16B col within 128B row

    for (int kt = 0; kt < 32; ++kt) {
        const int kofs = ks * 4096 + kt * 128;   // byte offset within 8192B row
        {                                        // A: 64 rows
            const int row = rst;
            gload16(Ab + (size_t)(m0 + row) * 8192 + kofs + (cb ^ ((row & 7) << 4)),
                    smem + tid * 16);
        }
#pragma unroll
        for (int c = 0; c < 4; ++c) {            // B: 256 rows (all of N)
            const int row = c * 64 + rst;
            gload16(Bb + (size_t)row * 8192 + kofs + (cb ^ ((row & 7) << 4)),
                    smem + 8192 + c * 8192 + tid * 16);
        }
        __syncthreads();
#pragma unroll
        for (int kk = 0; kk < 2; ++kk) {
            const int kb = kk * 64 + lg * 16;
            bf16x8 af[2], bfv[4];
#pragma unroll
            for (int mi = 0; mi < 2; ++mi) {
                const int r = wm + mi * 16 + lr;
                af[mi] = *(const bf16x8*)(smem + (((r * 128) + kb) ^ ((r & 7) << 4)));
            }
#pragma unroll
            for (int ni = 0; ni < 4; ++ni) {
                const int n = wn + ni * 16 + lr;
                bfv[ni] = *(const bf16x8*)(smem + 8192 + (((n * 128) + kb) ^ ((n & 7) << 4)));
            }
#pragma unroll
            for (int mi = 0; mi < 2; ++mi)
#pragma unroll
                for (int ni = 0; ni < 4; ++ni)
                    acc[mi][ni] = __builtin_amdgcn_mfma_f32_16x16x32_bf16(af[mi], bfv[ni], acc[mi][ni], 0, 0, 0);
        }
        __syncthreads();
    }
    // two contributions per out element (ks=0/1) -> commutative, deterministic
#pragma unroll
    for (int mi = 0; mi < 2; ++mi)
#pragma unroll
        for (int ni = 0; ni < 4; ++ni)
#pragma unroll
            for (int r = 0; r < 4; ++r) {
                const int row = m0 + wm + mi * 16 + lg * 4 + r;
                const int col = wn + ni * 16 + lr;
                unsafeAtomicAdd(&C[(size_t)row * 256 + col], acc[mi][ni][r]);
            }
}

extern "C" void kernel_launch(void* const* d_in, const int* in_sizes, int n_in,
                              void* d_out, int out_size, void* d_ws, size_t ws_size,
                              hipStream_t stream) {
    const float* x   = (const float*)d_in[0];   // (4,4096,256)
    const float* W   = (const float*)d_in[1];   // (16,256,256)
    const float* phi = (const float*)d_in[2];   // (4096,16)
    float* out = (float*)d_out;                 // (4,4096,256) f32

    char* ws = (char*)d_ws;
    u16*   WT   = (u16*)ws;                     // 2 MB
    u16*   Abuf = (u16*)(ws + (2u << 20));      // 128 MB
    float* U    = (float*)d_out;                // 16 MB, consumed by k3 before memset

    k0_wt  <<<256, 256, 0, stream>>>(W, WT);
    k1_sums<<<dim3(4, 256), 256, 0, stream>>>(x, phi, U);
    k2_scan<<<dim3(4, 16), 256, 0, stream>>>(U);
    k3_build<<<1024, 256, 0, stream>>>(x, phi, U, Abuf);
    hipMemsetAsync(d_out, 0, (size_t)out_size * sizeof(float), stream);
    k4_gemm<<<dim3(256, 2), 512, 0, stream>>>(Abuf, WT, out);
}

// Round 3
// 99.886 us; speedup vs baseline: 1.3357x; 1.2937x over previous
//
#include <hip/hip_runtime.h>

// STU layer: out[b,t,e] = sum_{k,d} phi[t,k] * C[b,t,k,d] * W[k,e,d],
//            C = cumsum_t(phi[t,k] * x[b,t,d])
// Fused: out = A @ WT^T (M=16384, Kdim=4096, N=256) where the A-tile
// (A[bt, d*16+k] = phi[t,k]*C[b,t,k,d]) is built on the fly in LDS from
// 16-step cumsum chains seeded by chunk-prefix states U. A is never
// materialized in HBM.
//   WT[e, d*16+k] = W[k,e,d]
// B=4, T=4096, D=256, K=16, chunk CH=16 (256 chunks/batch).

typedef __bf16 bf16x8 __attribute__((ext_vector_type(8)));
typedef float  f32x4  __attribute__((ext_vector_type(4)));
typedef unsigned short u16;

__device__ static inline u16 f2bf(float f) {          // RNE f32->bf16
    unsigned int u = __float_as_uint(f);
    u = (u + 0x7fffu + ((u >> 16) & 1u)) >> 16;
    return (u16)u;
}

__device__ static inline void gload16(const void* g, void* l) {
    __builtin_amdgcn_global_load_lds((const __attribute__((address_space(1))) void*)g,
                                     (__attribute__((address_space(3))) void*)l, 16, 0, 0);
}

// ---------------- k0: WT[e][d*16+k] = bf16(W[k][e][d]) ----------------
__global__ __launch_bounds__(256) void k0_wt(const float* __restrict__ W, u16* __restrict__ WT) {
    const int e = blockIdx.x, d = threadIdx.x;
    union { u16 u[16]; uint4 v[2]; } ob;
#pragma unroll
    for (int k = 0; k < 16; ++k)
        ob.u[k] = f2bf(W[((size_t)k * 256 + e) * 256 + d]);
    uint4* dst = (uint4*)(WT + (size_t)e * 4096 + d * 16);
    dst[0] = ob.v[0]; dst[1] = ob.v[1];
}

// ---------------- k1: chunk sums U[b,c,d,k] = sum_{s in 16-chunk} phi*x ----------------
__global__ __launch_bounds__(256) void k1_sums(const float* __restrict__ x,
                                               const float* __restrict__ phi,
                                               float* __restrict__ U) {
    __shared__ float phis[256];
    const int tid = threadIdx.x;
    const int b = blockIdx.x, c = blockIdx.y;
    const int t0 = c * 16;
    phis[tid] = phi[t0 * 16 + tid];
    __syncthreads();
    float acc[16];
#pragma unroll
    for (int k = 0; k < 16; ++k) acc[k] = 0.f;
    for (int s = 0; s < 16; ++s) {
        const float xv = x[(size_t)((b << 12) + t0 + s) * 256 + tid];
        union { float f[16]; float4 v[4]; } pv;
#pragma unroll
        for (int j = 0; j < 4; ++j) pv.v[j] = *(const float4*)&phis[s * 16 + j * 4];
#pragma unroll
        for (int k = 0; k < 16; ++k) acc[k] = fmaf(pv.f[k], xv, acc[k]);
    }
    float4* Up = (float4*)(U + ((size_t)((b * 256 + c) * 256 + tid)) * 16);
    union { float f[16]; float4 v[4]; } ov;
#pragma unroll
    for (int k = 0; k < 16; ++k) ov.f[k] = acc[k];
#pragma unroll
    for (int j = 0; j < 4; ++j) Up[j] = ov.v[j];
}

// ---------------- k2: exclusive scan of U over c (in place), 256 chunks ----------------
__global__ __launch_bounds__(256) void k2_scan(float* __restrict__ U) {
    const int b = blockIdx.x;                       // grid (4,16)
    const int dk = blockIdx.y * 256 + threadIdx.x;  // (d*16+k)
    float* base = U + (size_t)b * 1048576 + dk;
    float runv = 0.f;
    for (int g = 0; g < 16; ++g) {
        float v[16];
#pragma unroll
        for (int j = 0; j < 16; ++j) v[j] = base[(size_t)(g * 16 + j) * 4096];
#pragma unroll
        for (int j = 0; j < 16; ++j) {
            const float t = v[j];
            base[(size_t)(g * 16 + j) * 4096] = runv;
            runv += t;
        }
    }
}

// ---------------- k4: fused A-build + GEMM, K-split=2 via atomics ----------------
// BM=64, BN=256, BK=64; 512 threads = 8 waves. Waves 0-3: build A-tile
// (256 cumsum chains, one per lane). Waves 4-7: stage B via global_load_lds.
// Double-buffered (A 2x8KB, B 2x32KB = 80KB LDS), single barrier per K-step:
// next tile's chains+loads issue BEFORE current MFMA phase (T3-lite).
__global__ __launch_bounds__(512, 4) void k4_fused(const float* __restrict__ x,
                                                   const float* __restrict__ phi,
                                                   const float* __restrict__ U,
                                                   const u16* __restrict__ BT,
                                                   float* __restrict__ C) {
    __shared__ __align__(16) char smem[81920];   // A[2][8192] @0, B[2][32768] @16384
    const int tid = threadIdx.x;
    const int m0 = blockIdx.x * 64;              // global row base (bt)
    const int ks = blockIdx.y;                   // kdim half
    const int b  = m0 >> 12, t0 = m0 & 4095, c0 = t0 >> 4;
    const int w = tid >> 6, l = tid & 63;
    const int wm = (w >> 2) * 32, wn = (w & 3) * 64;
    const int lg = l >> 4, lr = l & 15;
    f32x4 acc[2][4] = {};

    // ---- chain-lane constants (waves 0-3): chain = (chunk=w, d-local=lg, k=lr)
    float p[16];
    if (w < 4) {
#pragma unroll
        for (int s = 0; s < 16; ++s) p[s] = phi[(t0 + w * 16 + s) * 16 + lr];
    }
    const char* Bb = (const char*)BT;
    const int tl = tid & 255;
    const int colb = (lg * 16 + lr) * 2;         // A-tile column byte for chain lane

    auto stageB = [&](int kt, int buf) {         // waves 4-7: 8 x gload16 each
        const int kofs = ks * 4096 + kt * 128;   // byte offset in 8192B WT row
#pragma unroll
        for (int c = 0; c < 8; ++c) {
            const int row = c * 32 + (tl >> 3);
            gload16(Bb + (size_t)row * 8192 + kofs + (((tl & 7) * 16) ^ ((row & 7) << 4)),
                    smem + 16384 + buf * 32768 + c * 4096 + tl * 16);
        }
    };
    auto chains = [&](int kt, int buf) {         // waves 0-3: one 16-step chain
        const int d = ks * 128 + kt * 4 + lg;
        float run = U[(((size_t)(b * 256 + c0 + w)) * 256 + d) * 16 + lr];
        char* Ab = smem + buf * 8192 + w * 2048; // chunk w -> rows w*16..w*16+15
#pragma unroll
        for (int s = 0; s < 16; ++s) {
            const float xv = x[(size_t)(m0 + w * 16 + s) * 256 + d];
            run = fmaf(p[s], xv, run);
            *(u16*)(Ab + s * 128 + (colb ^ ((s & 7) << 4))) = f2bf(p[s] * run);
        }
    };

    // prologue: fill buffer 0
    if (w >= 4) stageB(0, 0); else chains(0, 0);
    __syncthreads();

    for (int kt = 0; kt < 32; ++kt) {
        const int cur = kt & 1;
        if (kt < 31) {                            // issue next tile first
            if (w >= 4) stageB(kt + 1, cur ^ 1);
            else        chains(kt + 1, cur ^ 1);
        }
        const char* Abase = smem + cur * 8192;
        const char* Bbase = smem + 16384 + cur * 32768;
#pragma unroll
        for (int kk = 0; kk < 2; ++kk) {
            const int kb = kk * 64 + lg * 16;
            bf16x8 af[2], bfv[4];
#pragma unroll
            for (int mi = 0; mi < 2; ++mi) {
                const int r = wm + mi * 16 + lr;
                af[mi] = *(const bf16x8*)(Abase + r * 128 + (kb ^ ((r & 7) << 4)));
            }
#pragma unroll
            for (int ni = 0; ni < 4; ++ni) {
                const int n = wn + ni * 16 + lr;
                bfv[ni] = *(const bf16x8*)(Bbase + n * 128 + (kb ^ ((n & 7) << 4)));
            }
#pragma unroll
            for (int mi = 0; mi < 2; ++mi)
#pragma unroll
                for (int ni = 0; ni < 4; ++ni)
                    acc[mi][ni] = __builtin_amdgcn_mfma_f32_16x16x32_bf16(af[mi], bfv[ni], acc[mi][ni], 0, 0, 0);
        }
        __syncthreads();
    }

    // epilogue: two contributions per out element (ks=0/1), commutative f32 adds
#pragma unroll
    for (int mi = 0; mi < 2; ++mi)
#pragma unroll
        for (int ni = 0; ni < 4; ++ni)
#pragma unroll
            for (int r = 0; r < 4; ++r) {
                const int row = m0 + wm + mi * 16 + lg * 4 + r;
                const int col = wn + ni * 16 + lr;
                unsafeAtomicAdd(&C[(size_t)row * 256 + col], acc[mi][ni][r]);
            }
}

extern "C" void kernel_launch(void* const* d_in, const int* in_sizes, int n_in,
                              void* d_out, int out_size, void* d_ws, size_t ws_size,
                              hipStream_t stream) {
    const float* x   = (const float*)d_in[0];   // (4,4096,256)
    const float* W   = (const float*)d_in[1];   // (16,256,256)
    const float* phi = (const float*)d_in[2];   // (4096,16)
    float* out = (float*)d_out;                 // (4,4096,256) f32

    char* ws = (char*)d_ws;
    u16*   WT = (u16*)ws;                       // 2 MB
    float* U  = (float*)(ws + (2u << 20));      // 16 MB

    k0_wt  <<<256, 256, 0, stream>>>(W, WT);
    k1_sums<<<dim3(4, 256), 256, 0, stream>>>(x, phi, U);
    k2_scan<<<dim3(4, 16), 256, 0, stream>>>(U);
    hipMemsetAsync(d_out, 0, (size_t)out_size * sizeof(float), stream);
    k4_fused<<<dim3(256, 2), 512, 0, stream>>>(x, phi, U, WT, out);
}